// Round 1
// baseline (172.584 us; speedup 1.0000x reference)
//
#include <hip/hip_runtime.h>

// CG tensor product: out[L] sections of concatenated triples.
// C=512 channels, L_MAX=3, 23 triples. Output = 99*C^2 floats (~104 MB) -> write-BW bound.
// Strategy: block owns one i (half j-range), precompute y[n,M] = sum_m cg[M,n,m]*xi[m]
// in LDS (567 floats), each thread handles one j: p[M] = sum_n y[n,M]*xj[n].

#define CCH 512
#define C2 (512 * 512)

struct Ptrs {
    const float* x[4];
    const float* cg[23];
};

// F(t, l1, l2, L, out_base_in_C2_units, y_offset)
#define TRIPLE_LIST(F) \
    F(0, 0, 0, 0, 0, 0) \
    F(1, 0, 1, 1, 4, 1) \
    F(2, 0, 2, 2, 22, 10) \
    F(3, 0, 3, 3, 57, 35) \
    F(4, 1, 1, 0, 1, 84) \
    F(5, 1, 1, 1, 7, 87) \
    F(6, 1, 1, 2, 27, 96) \
    F(7, 1, 2, 1, 10, 111) \
    F(8, 1, 2, 2, 32, 126) \
    F(9, 1, 2, 3, 64, 151) \
    F(10, 1, 3, 2, 37, 186) \
    F(11, 1, 3, 3, 71, 221) \
    F(12, 2, 2, 0, 2, 270) \
    F(13, 2, 2, 1, 13, 275) \
    F(14, 2, 2, 2, 42, 290) \
    F(15, 2, 2, 3, 78, 315) \
    F(16, 2, 3, 1, 16, 350) \
    F(17, 2, 3, 2, 47, 371) \
    F(18, 2, 3, 3, 85, 406) \
    F(19, 3, 3, 0, 3, 455) \
    F(20, 3, 3, 1, 19, 462) \
    F(21, 3, 3, 2, 52, 483) \
    F(22, 3, 3, 3, 92, 518)

// xj register index base per l2: rows [x0 | x1(3) | x2(5) | x3(7)]
#define XBASE(L2) ((L2) == 0 ? 0 : ((L2) == 1 ? 1 : ((L2) == 2 ? 4 : 9)))

__global__ __launch_bounds__(256) void cg_tp_kernel(Ptrs p, float* __restrict__ out) {
    __shared__ float xT[16][256];  // transposed x rows for this block's 256 j's
    __shared__ float ysh[567];     // i-side factors

    const int tid = threadIdx.x;
    const int b = blockIdx.x;
    const int i = b >> 1;
    const int j0 = (b & 1) << 8;

    // ---- stage xT[k][j'] = x_l[(j0+j')* (2l+1) + m], k = XBASE(l)+m ----
    {
        const float* xp0 = p.x[0] + j0;
        xT[0][tid] = xp0[tid];

        const float* xp1 = p.x[1] + j0 * 3;
        #pragma unroll
        for (int r = 0; r < 3; ++r) {
            int idx = tid + r * 256;
            xT[1 + idx % 3][idx / 3] = xp1[idx];
        }
        const float* xp2 = p.x[2] + j0 * 5;
        #pragma unroll
        for (int r = 0; r < 5; ++r) {
            int idx = tid + r * 256;
            xT[4 + idx % 5][idx / 5] = xp2[idx];
        }
        const float* xp3 = p.x[3] + j0 * 7;
        #pragma unroll
        for (int r = 0; r < 7; ++r) {
            int idx = tid + r * 256;
            xT[9 + idx % 7][idx / 7] = xp3[idx];
        }
    }

    // ---- compute y: ysh[yoff + n*(2L+1) + M] = sum_m cg[M][n][m] * xi[m] ----
    for (int e = tid; e < 567; e += 256) {
#define YC(T, L1, L2, LL, OB, YO)                                              \
        if (e >= (YO) && e < (YO) + (2 * L2 + 1) * (2 * LL + 1)) {             \
            const int local = e - (YO);                                        \
            const int n = local / (2 * LL + 1);                                \
            const int M = local % (2 * LL + 1);                                \
            const float* cg = p.cg[T] + (M * (2 * L2 + 1) + n) * (2 * L1 + 1); \
            const float* xi = p.x[L1] + i * (2 * L1 + 1);                      \
            float s = 0.f;                                                     \
            _Pragma("unroll")                                                  \
            for (int m = 0; m < 2 * L1 + 1; ++m) s = fmaf(cg[m], xi[m], s);    \
            ysh[e] = s;                                                        \
        }
        TRIPLE_LIST(YC)
#undef YC
    }

    __syncthreads();

    // ---- per-thread j row into registers ----
    float xj[16];
    #pragma unroll
    for (int k = 0; k < 16; ++k) xj[k] = xT[k][tid];

    const int pair = b * 256 + tid;  // = i*512 + j

    // ---- main: for each triple, p[M] = sum_n y[n,M]*xj[n]; store ----
#define TC(T, L1, L2, LL, OB, YO)                                              \
    {                                                                          \
        constexpr int NW = 2 * LL + 1;                                         \
        float acc[NW] = {};                                                    \
        const float* y = ysh + (YO);                                           \
        _Pragma("unroll")                                                      \
        for (int n = 0; n < 2 * L2 + 1; ++n) {                                 \
            const float xv = xj[XBASE(L2) + n];                                \
            _Pragma("unroll")                                                  \
            for (int M = 0; M < NW; ++M)                                       \
                acc[M] = fmaf(y[n * NW + M], xv, acc[M]);                      \
        }                                                                      \
        float* o = out + (size_t)(OB) * C2 + (size_t)pair * NW;                \
        _Pragma("unroll")                                                      \
        for (int M = 0; M < NW; ++M) o[M] = acc[M];                            \
    }
    TRIPLE_LIST(TC)
#undef TC
}

extern "C" void kernel_launch(void* const* d_in, const int* in_sizes, int n_in,
                              void* d_out, int out_size, void* d_ws, size_t ws_size,
                              hipStream_t stream) {
    Ptrs p;
    for (int l = 0; l < 4; ++l) p.x[l] = (const float*)d_in[l];
    for (int t = 0; t < 23; ++t) p.cg[t] = (const float*)d_in[4 + t];
    cg_tp_kernel<<<dim3(1024), dim3(256), 0, stream>>>(p, (float*)d_out);
}

// Round 2
// 170.735 us; speedup vs baseline: 1.0108x; 1.0108x over previous
//
#include <hip/hip_runtime.h>

// CG tensor product: out[L] sections of concatenated triples.
// C=512, L_MAX=3, 23 triples. Output = 99*C^2 fp32 (~104 MB) -> write-BW bound.
// Block owns (i, half j-range). y[n,M] = sum_m cg[M,n,m]*xi[m] in LDS (567 fl).
// Thread computes acc[M] = sum_n y[n,M]*xj[n] for its j, then outputs are
// round-tripped through an LDS staging tile so global stores are coalesced
// float4s (round-1 lane-strided dword stores were ~5x transaction-inflated).

#define C2 (512 * 512)

struct Ptrs {
    const float* x[4];
    const float* cg[23];
};

// F(t, l1, l2, L, out_base_in_C2_units, y_offset)
#define TRIPLE_LIST(F) \
    F(0, 0, 0, 0, 0, 0) \
    F(1, 0, 1, 1, 4, 1) \
    F(2, 0, 2, 2, 22, 10) \
    F(3, 0, 3, 3, 57, 35) \
    F(4, 1, 1, 0, 1, 84) \
    F(5, 1, 1, 1, 7, 87) \
    F(6, 1, 1, 2, 27, 96) \
    F(7, 1, 2, 1, 10, 111) \
    F(8, 1, 2, 2, 32, 126) \
    F(9, 1, 2, 3, 64, 151) \
    F(10, 1, 3, 2, 37, 186) \
    F(11, 1, 3, 3, 71, 221) \
    F(12, 2, 2, 0, 2, 270) \
    F(13, 2, 2, 1, 13, 275) \
    F(14, 2, 2, 2, 42, 290) \
    F(15, 2, 2, 3, 78, 315) \
    F(16, 2, 3, 1, 16, 350) \
    F(17, 2, 3, 2, 47, 371) \
    F(18, 2, 3, 3, 85, 406) \
    F(19, 3, 3, 0, 3, 455) \
    F(20, 3, 3, 1, 19, 462) \
    F(21, 3, 3, 2, 52, 483) \
    F(22, 3, 3, 3, 92, 518)

// xj register index base per l2: rows [x0 | x1(3) | x2(5) | x3(7)]
#define XBASE(L2) ((L2) == 0 ? 0 : ((L2) == 1 ? 1 : ((L2) == 2 ? 4 : 9)))

__global__ __launch_bounds__(256) void cg_tp_kernel(Ptrs p, float* __restrict__ out) {
    // smem serves two phases:
    //   phase 1: xT[16][256] transposed x rows for this block's 256 j's
    //   phase 2: two staging buffers of 7*256 floats each (double-buffered)
    __shared__ float smem[16 * 256];
    __shared__ float ysh[567];  // i-side factors

    const int tid = threadIdx.x;
    const int b = blockIdx.x;
    const int i = b >> 1;
    const int j0 = (b & 1) << 8;

    // ---- stage xT[k][j'] = x_l[(j0+j')*(2l+1) + m], k = XBASE(l)+m ----
    {
        float* xT = smem;
        const float* xp0 = p.x[0] + j0;
        xT[0 * 256 + tid] = xp0[tid];

        const float* xp1 = p.x[1] + j0 * 3;
        #pragma unroll
        for (int r = 0; r < 3; ++r) {
            int idx = tid + r * 256;
            xT[(1 + idx % 3) * 256 + idx / 3] = xp1[idx];
        }
        const float* xp2 = p.x[2] + j0 * 5;
        #pragma unroll
        for (int r = 0; r < 5; ++r) {
            int idx = tid + r * 256;
            xT[(4 + idx % 5) * 256 + idx / 5] = xp2[idx];
        }
        const float* xp3 = p.x[3] + j0 * 7;
        #pragma unroll
        for (int r = 0; r < 7; ++r) {
            int idx = tid + r * 256;
            xT[(9 + idx % 7) * 256 + idx / 7] = xp3[idx];
        }
    }

    // ---- compute y: ysh[yoff + n*(2L+1) + M] = sum_m cg[M][n][m] * xi[m] ----
    for (int e = tid; e < 567; e += 256) {
#define YC(T, L1, L2, LL, OB, YO)                                              \
        if (e >= (YO) && e < (YO) + (2 * L2 + 1) * (2 * LL + 1)) {             \
            const int local = e - (YO);                                        \
            const int n = local / (2 * LL + 1);                                \
            const int M = local % (2 * LL + 1);                                \
            const float* cg = p.cg[T] + (M * (2 * L2 + 1) + n) * (2 * L1 + 1); \
            const float* xi = p.x[L1] + i * (2 * L1 + 1);                      \
            float s = 0.f;                                                     \
            _Pragma("unroll")                                                  \
            for (int m = 0; m < 2 * L1 + 1; ++m) s = fmaf(cg[m], xi[m], s);    \
            ysh[e] = s;                                                        \
        }
        TRIPLE_LIST(YC)
#undef YC
    }

    __syncthreads();

    // ---- per-thread j row into registers ----
    float xj[16];
    #pragma unroll
    for (int k = 0; k < 16; ++k) xj[k] = smem[k * 256 + tid];

    __syncthreads();  // xT fully consumed; smem may now be reused for staging

    // ---- main: per triple, acc[M] = sum_n y[n,M]*xj[n]; LDS-stage; coalesced store.
    // Double-buffered staging: triple T uses smem + (T&1)*7*256. Reads of buffer
    // (T&1) finish before barrier T+1; next write of that buffer is after barrier
    // T+1 (in triple T+2) -> race-free with ONE barrier per triple.
#define TC(T, L1, L2, LL, OB, YO)                                              \
    {                                                                          \
        constexpr int NW = 2 * LL + 1;                                         \
        float acc[NW] = {};                                                    \
        const float* y = ysh + (YO);                                           \
        _Pragma("unroll")                                                      \
        for (int n = 0; n < 2 * L2 + 1; ++n) {                                 \
            const float xv = xj[XBASE(L2) + n];                                \
            _Pragma("unroll")                                                  \
            for (int M = 0; M < NW; ++M)                                       \
                acc[M] = fmaf(y[n * NW + M], xv, acc[M]);                      \
        }                                                                      \
        float* stg = smem + ((T) & 1) * (7 * 256);                             \
        _Pragma("unroll")                                                      \
        for (int M = 0; M < NW; ++M) stg[tid * NW + M] = acc[M];               \
        __syncthreads();                                                       \
        const float4* s4 = (const float4*)stg;                                 \
        float4* dst = (float4*)(out + (size_t)(OB) * C2 + (size_t)b * (256 * NW)); \
        for (int k = tid; k < 64 * NW; k += 256) dst[k] = s4[k];               \
    }
    TRIPLE_LIST(TC)
#undef TC
}

extern "C" void kernel_launch(void* const* d_in, const int* in_sizes, int n_in,
                              void* d_out, int out_size, void* d_ws, size_t ws_size,
                              hipStream_t stream) {
    Ptrs p;
    for (int l = 0; l < 4; ++l) p.x[l] = (const float*)d_in[l];
    for (int t = 0; t < 23; ++t) p.cg[t] = (const float*)d_in[4 + t];
    cg_tp_kernel<<<dim3(1024), dim3(256), 0, stream>>>(p, (float*)d_out);
}